// Round 7
// baseline (201.233 us; speedup 1.0000x reference)
//
#include <hip/hip_runtime.h>

// NONA: out = softmax(-cdist(x, x_n), axis=1) @ y
//   x[4096,1024] f32, x_n[8192,1024] f32, y[8192,128] f32, log_T unused.
//
// R7 redesign (fused kernel hit a register wall: O-acc [R][8] forces R<=2 per
// wave -> S-GEMM stuck at m97-class ~26% of peak; MfmaUtil == %-of-peak):
//  * k1 (nona_s): pure 256x256-tile bf16 GEMM, 8 waves (2x4), per-wave 128x64,
//    Sacc[8][4] frags (m201 geometry, 0.375 reads/MFMA). R5's PROVEN
//    counted-vmcnt K-loop skeleton. Epilogue: w=exp(-sqrt(max(d2,0))),
//    store W bf16 panel + per-(coltile,row) sum partials Lpart.
//  * k2 (nona_pv): Opart += W @ y streaming MFMA, frags direct from global
//    (W row-major 16B frags; yT 16B frags - R5's PV layout), 8-wave K-split
//    + LDS reduce. No staging, no barriers in the hot loop.
//  * M processed in np panels (W = 64/np MiB reused; k1(p);k2(p) interleaved,
//    stream-ordered => deterministic). np=2 fits the known ws>=61MiB budget
//    and keeps the W panel L3-resident for k2.
//  * lred: l = sum_ct Lpart; divide: out = Opart / l.
//
// ws layout (bytes): xb@0 (8Mi) | xnb@8Mi (16Mi) | yT@24Mi (2Mi) |
//   xsq@26Mi (16Ki) | xnsq@+16Ki (32Ki) | l@+48Ki (16Ki) | Lpart@26Mi+64Ki
//   (512Ki) | Opart@27Mi (2Mi) | W@29Mi (64/np Mi)

#define N_ 4096
#define M_ 8192
#define D_ 1024
#define C_ 128
#define BK 64
#define NKK (D_ / BK)        // 16

typedef __bf16 bf16;
typedef __attribute__((ext_vector_type(8))) __bf16 bf16x8;
typedef __attribute__((ext_vector_type(4))) __bf16 bf16x4;
typedef __attribute__((ext_vector_type(4))) float f32x4;

__device__ __forceinline__ void async_copy16(const bf16* gp, void* lp) {
  __builtin_amdgcn_global_load_lds(
      (__attribute__((address_space(1))) void*)const_cast<bf16*>(gp),
      (__attribute__((address_space(3))) void*)lp, 16, 0, 0);
}

// Swizzled LDS byte offset for a [rows][64]-bf16 tile (128 B rows):
// 16B-granule XOR with row&7 (proven 0-conflict in R1-R6).
__device__ __forceinline__ int swz(int row, int gran) {
  return (row << 7) + ((gran ^ (row & 7)) << 4);
}

// Stage a [256][64]-bf16 tile (32 KiB) global->LDS with 512 threads,
// source pre-swizzled (linear LDS dest, rule #21). 4 loads/thread.
__device__ __forceinline__ void stage32(const bf16* src, int ld, char* lds, int tid) {
  const int lane = tid & 63, wave = tid >> 6;
#pragma unroll
  for (int j = 0; j < 4; ++j) {
    const int ch  = j * 8 + wave;            // wave-uniform chunk id (0..31)
    const int off = ch * 1024 + lane * 16;   // linear byte in tile
    const int row = off >> 7;
    const int grs = ((off >> 4) & 7) ^ (row & 7);
    async_copy16(src + (size_t)row * ld + grs * 8, lds + ch * 1024);
  }
}

// ---- k1: W[panel] = exp(-cdist) for a 256x256 tile; Lpart row-sum partials
__global__ __launch_bounds__(512, 2)
void nona_s(const bf16* __restrict__ xb, const bf16* __restrict__ xnb,
            const float* __restrict__ xsq, const float* __restrict__ xnsq,
            bf16* __restrict__ W, float* __restrict__ Lpart,
            int colbase0, int Mpanel)
{
  __shared__ __align__(16) char Lds[131072];
  char* const A0 = Lds;             // x  [256][64], even kk
  char* const A1 = Lds + 32768;     // x  [256][64], odd kk
  char* const B0 = Lds + 65536;     // xn [256][64], even kk
  char* const B1 = Lds + 98304;     // xn [256][64], odd kk

  const int tid  = threadIdx.x;
  const int lane = tid & 63;
  const int wave = tid >> 6;          // 8 waves: 2 (wr) x 4 (wc)
  const int wr = wave >> 2, wc = wave & 3;
  const int g = lane >> 4, c = lane & 15;

  const int rb = blockIdx.x & 15;     // 16 row tiles; bid%8 -> XCD shares rb slabs
  const int cb = blockIdx.x >> 4;
  const int row0  = rb * 256;
  const int colg0 = colbase0 + cb * 256;   // global xn col of tile

  const bf16* xA = xb + (size_t)row0 * D_;
  const bf16* xB = xnb + (size_t)colg0 * D_;

  f32x4 Sacc[8][4];
  const f32x4 zero = {0.f, 0.f, 0.f, 0.f};
#pragma unroll
  for (int rf = 0; rf < 8; ++rf)
#pragma unroll
    for (int cf = 0; cf < 4; ++cf) Sacc[rf][cf] = zero;

  // S^T step: Sacc[rf][cf] = mfma(A=xn_frag, B=x_frag) ->
  // lane holds S[xn = wc*64+cf*16+g*4+r][x = wr*128+rf*16+c]
  auto qkStep = [&](const char* Ac, const char* Bc) {
#pragma unroll
    for (int ks = 0; ks < 2; ++ks) {
      bf16x8 af[8];
#pragma unroll
      for (int rf = 0; rf < 8; ++rf)
        af[rf] = *(const bf16x8*)(Ac + swz(wr * 128 + rf * 16 + c, ks * 4 + g));
      __builtin_amdgcn_s_setprio(1);
#pragma unroll
      for (int cf = 0; cf < 4; ++cf) {
        bf16x8 bv = *(const bf16x8*)(Bc + swz(wc * 64 + cf * 16 + c, ks * 4 + g));
#pragma unroll
        for (int rf = 0; rf < 8; ++rf)
          Sacc[rf][cf] = __builtin_amdgcn_mfma_f32_16x16x32_bf16(bv, af[rf], Sacc[rf][cf], 0, 0, 0);
      }
      __builtin_amdgcn_s_setprio(0);
    }
  };

  stage32(xA, D_, A0, tid);           // stage(0): 8 loads/thread
  stage32(xB, D_, B0, tid);

#pragma unroll 1
  for (int kk = 0; kk < NKK - 1; ++kk) {
    // WAR: dest buf last read at qkStep(kk-1), sealed by bar2 of kk-1.
    stage32(xA + (kk + 1) * BK, D_, (kk & 1) ? A0 : A1, tid);
    stage32(xB + (kk + 1) * BK, D_, (kk & 1) ? B0 : B1, tid);
    asm volatile("s_waitcnt vmcnt(8)" ::: "memory");   // own stage(kk) landed
    __builtin_amdgcn_s_barrier();                      // bar1: all stage(kk) landed
    __builtin_amdgcn_sched_barrier(0);
    qkStep((kk & 1) ? A1 : A0, (kk & 1) ? B1 : B0);
    __builtin_amdgcn_sched_barrier(0);
    __builtin_amdgcn_s_barrier();                      // bar2: buf kk readers done
  }
  // peeled kk = 15 (odd): A1/B1
  asm volatile("s_waitcnt vmcnt(0)" ::: "memory");
  __builtin_amdgcn_s_barrier();
  __builtin_amdgcn_sched_barrier(0);
  qkStep(A1, B1);

  // ---- epilogue: w = exp(-sqrt(max(xsq + xnsq - 2*dot, 0))), store W, Lpart
  float xsr[8];
#pragma unroll
  for (int rf = 0; rf < 8; ++rf)
    xsr[rf] = xsq[row0 + wr * 128 + rf * 16 + c];

  float lsum[8] = {};
#pragma unroll
  for (int cf = 0; cf < 4; ++cf) {
    const float4 nsq4 = *(const float4*)(xnsq + colg0 + wc * 64 + cf * 16 + g * 4);
#pragma unroll
    for (int rf = 0; rf < 8; ++rf) {
      bf16x4 pk;
#pragma unroll
      for (int r = 0; r < 4; ++r) {
        float d2 = xsr[rf] + ((const float*)&nsq4)[r] - 2.0f * Sacc[rf][cf][r];
        d2 = fmaxf(d2, 0.0f);
        const float wv = __expf(-sqrtf(d2));
        lsum[rf] += wv;
        pk[r] = (bf16)wv;
      }
      *(bf16x4*)(W + (size_t)(row0 + wr * 128 + rf * 16 + c) * Mpanel
                   + cb * 256 + wc * 64 + cf * 16 + g * 4) = pk;
    }
  }

  // Lpart[ct][row]: reduce lane-partials (xor 16/32 over g) then the 4 wc waves
  __syncthreads();                    // K-loop LDS readers done -> reuse Lds
  float* Lred = (float*)Lds;          // [4 wc][256 rows]
#pragma unroll
  for (int rf = 0; rf < 8; ++rf) {
    float v = lsum[rf];
    v += __shfl_xor(v, 16);
    v += __shfl_xor(v, 32);
    if (g == 0) Lred[wc * 256 + wr * 128 + rf * 16 + c] = v;
  }
  __syncthreads();
  if (tid < 256)
    Lpart[(size_t)(colg0 >> 8) * N_ + row0 + tid] =
        Lred[tid] + Lred[256 + tid] + Lred[512 + tid] + Lred[768 + tid];
}

// ---- k2: Opart(+)= W @ y for one panel. 32 rows/block, 8 waves split K.
__global__ __launch_bounds__(512, 2)
void nona_pv(const bf16* __restrict__ W, const bf16* __restrict__ yT,
             float* __restrict__ Opart, int colbase0, int Mpanel, int first)
{
  __shared__ float red[8][32][128];   // 128 KiB
  const int tid  = threadIdx.x;
  const int lane = tid & 63;
  const int wave = tid >> 6;
  const int g = lane >> 4, c = lane & 15;
  const int row0 = blockIdx.x * 32;
  const int KW = Mpanel >> 3;         // per-wave K range
  const int k0 = wave * KW;

  f32x4 O[2][8];
  const f32x4 zero = {0.f, 0.f, 0.f, 0.f};
#pragma unroll
  for (int rf = 0; rf < 2; ++rf)
#pragma unroll
    for (int cc = 0; cc < 8; ++cc) O[rf][cc] = zero;

#pragma unroll 2
  for (int kk = 0; kk < KW; kk += 32) {
    const int k = k0 + kk;
    bf16x8 pa[2];
#pragma unroll
    for (int rf = 0; rf < 2; ++rf)
      pa[rf] = *(const bf16x8*)(W + (size_t)(row0 + rf * 16 + c) * Mpanel + k + g * 8);
#pragma unroll
    for (int cc = 0; cc < 8; ++cc) {
      bf16x8 vb = *(const bf16x8*)(yT + (size_t)(cc * 16 + c) * M_ + colbase0 + k + g * 8);
#pragma unroll
      for (int rf = 0; rf < 2; ++rf)
        O[rf][cc] = __builtin_amdgcn_mfma_f32_16x16x32_bf16(pa[rf], vb, O[rf][cc], 0, 0, 0);
    }
  }

  // out row = row0 + rf*16 + g*4 + r, col = cc*16 + c  (R5 PV layout)
#pragma unroll
  for (int rf = 0; rf < 2; ++rf)
#pragma unroll
    for (int cc = 0; cc < 8; ++cc)
#pragma unroll
      for (int r = 0; r < 4; ++r)
        red[wave][rf * 16 + g * 4 + r][cc * 16 + c] = O[rf][cc][r];
  __syncthreads();

#pragma unroll
  for (int i = 0; i < 8; ++i) {
    const int idx = tid * 8 + i;      // 0..4095
    const int row = idx >> 7, col = idx & 127;
    float v = 0.f;
#pragma unroll
    for (int w = 0; w < 8; ++w) v += red[w][row][col];
    const size_t o = (size_t)(row0 + row) * C_ + col;
    if (first) Opart[o] = v; else Opart[o] += v;
  }
}

// row-wise: f32 -> bf16 copy + exact f32 squared norm
__global__ void prep_rows(const float* __restrict__ src, bf16* __restrict__ dst,
                          float* __restrict__ sq)
{
  const int row = blockIdx.x;
  const int t = threadIdx.x;                   // 256 threads, 4 f32 each
  const float4 v = reinterpret_cast<const float4*>(src + (size_t)row * D_)[t];
  float ss = v.x * v.x + v.y * v.y + v.z * v.z + v.w * v.w;
  bf16x4 hv;
  hv[0] = (bf16)v.x; hv[1] = (bf16)v.y; hv[2] = (bf16)v.z; hv[3] = (bf16)v.w;
  *reinterpret_cast<bf16x4*>(dst + (size_t)row * D_ + t * 4) = hv;
#pragma unroll
  for (int o = 32; o > 0; o >>= 1) ss += __shfl_down(ss, o);
  __shared__ float red[4];
  if ((t & 63) == 0) red[t >> 6] = ss;
  __syncthreads();
  if (t == 0) sq[row] = red[0] + red[1] + red[2] + red[3];
}

// y[8192][128] f32 -> yT[128][8192] bf16
__global__ void prep_yT(const float* __restrict__ y, bf16* __restrict__ yT)
{
  __shared__ bf16 tile[C_][72];
  const int m0 = blockIdx.x * 64;
  const int t = threadIdx.x;
#pragma unroll
  for (int i = 0; i < 32; ++i) {
    const int idx = i * 256 + t;               // 0..8191
    const int ml = idx >> 7, cc = idx & 127;
    tile[cc][ml] = (bf16)y[(size_t)(m0 + ml) * C_ + cc];
  }
  __syncthreads();
#pragma unroll
  for (int i = 0; i < 32; ++i) {
    const int idx = i * 256 + t;
    const int cc = idx >> 6, ml = idx & 63;
    yT[(size_t)cc * M_ + m0 + ml] = tile[cc][ml];
  }
}

__global__ void lred(const float* __restrict__ Lpart, float* __restrict__ l)
{
  const int row = blockIdx.x * 256 + threadIdx.x;  // < N_
  float s = 0.f;
#pragma unroll
  for (int ct = 0; ct < M_ / 256; ++ct) s += Lpart[(size_t)ct * N_ + row];
  l[row] = s;
}

__global__ void divide(const float* __restrict__ Opart, const float* __restrict__ l,
                       float* __restrict__ out)
{
  const int i = blockIdx.x * 256 + threadIdx.x;    // < N_*C_
  out[i] = Opart[i] / l[i >> 7];
}

extern "C" void kernel_launch(void* const* d_in, const int* in_sizes, int n_in,
                              void* d_out, int out_size, void* d_ws, size_t ws_size,
                              hipStream_t stream)
{
  const float* x  = (const float*)d_in[0];
  const float* xn = (const float*)d_in[1];
  const float* y  = (const float*)d_in[2];
  // d_in[3] = log_T: computed-but-unused in the reference forward.
  float* out = (float*)d_out;

  char* ws = (char*)d_ws;
  bf16*  xb    = (bf16*)(ws);
  bf16*  xnb   = (bf16*)(ws + (size_t)8  * 1024 * 1024);
  bf16*  yT    = (bf16*)(ws + (size_t)24 * 1024 * 1024);
  float* xsq   = (float*)(ws + (size_t)26 * 1024 * 1024);
  float* xnsq  = (float*)(ws + (size_t)26 * 1024 * 1024 + 16 * 1024);
  float* l     = (float*)(ws + (size_t)26 * 1024 * 1024 + 48 * 1024);
  float* Lpart = (float*)(ws + (size_t)26 * 1024 * 1024 + 64 * 1024);
  float* Opart = (float*)(ws + (size_t)27 * 1024 * 1024);
  bf16*  W     = (bf16*)(ws + (size_t)29 * 1024 * 1024);

  // panel count: W = 64/np MiB @ 29 MiB. np=2 needs 61 MiB (known-safe tier).
  const size_t MB = 1024 * 1024;
  int np;
  if      (ws_size >= 62 * MB) np = 2;
  else if (ws_size >= 46 * MB) np = 4;
  else if (ws_size >= 38 * MB) np = 8;
  else                         np = 16;
  const int Mpanel = M_ / np;

  prep_rows<<<N_, 256, 0, stream>>>(x, xb, xsq);
  prep_rows<<<M_, 256, 0, stream>>>(xn, xnb, xnsq);
  prep_yT<<<M_ / 64, 256, 0, stream>>>(y, yT);

  for (int p = 0; p < np; ++p) {
    nona_s<<<16 * (Mpanel / 256), 512, 0, stream>>>(xb, xnb, xsq, xnsq, W, Lpart,
                                                    p * Mpanel, Mpanel);
    nona_pv<<<N_ / 32, 512, 0, stream>>>(W, yT, Opart, p * Mpanel, Mpanel, p == 0);
  }
  lred<<<N_ / 256, 256, 0, stream>>>(Lpart, l);
  divide<<<(N_ * C_) / 256, 256, 0, stream>>>(Opart, l, out);
}